// Round 6
// baseline (120.433 us; speedup 1.0000x reference)
//
#include <hip/hip_runtime.h>
#include <math.h>

#define N_NODES 3072
#define H_HEADS 8
#define IN_FEAT 64
#define OUT_FEAT 16
#define WORDS_PER_ROW 96               // 3072/32
#define MAXD 96                        // per-row list cap; Poisson(32): P(>96) ~ 1e-19
#define SCATTER_BLOCKS 384             // 384*256 = 98304 = E
#define WH_NPB 16                      // nodes per block in the Wh branch
#define WH_BLOCKS (N_NODES / WH_NPB)   // 192

// ---------------------------------------------------------------------------
// Fused: blocks [0, SCATTER_BLOCKS) scatter edges (dedup via bitmask: append
// to row list only when the bit is newly set); blocks [SCATTER_BLOCKS, ...)
// compute Wh, e1t, e2t (head-minor so main can gather all heads in one 32B).
// ---------------------------------------------------------------------------
__launch_bounds__(256)
__global__ void scatter_and_wh_kernel(const int* __restrict__ ei, int E,
                                      int* __restrict__ cnt,
                                      unsigned int* __restrict__ bits,
                                      int* __restrict__ adj,
                                      const float* __restrict__ hfeat,
                                      const float* __restrict__ W,
                                      const float* __restrict__ a,
                                      float* __restrict__ Wh,
                                      float* __restrict__ e1t,
                                      float* __restrict__ e2t) {
    __shared__ __align__(16) float Wt[H_HEADS][OUT_FEAT][68];  // pad 64->68: no 2^k stride
    __shared__ __align__(16) float hs[WH_NPB][IN_FEAT];

    int tid = threadIdx.x;
    if (blockIdx.x < SCATTER_BLOCKS) {
        int e = blockIdx.x * 256 + tid;
        if (e < E) {
            int r = ei[e];       // row (softmax source)
            int c = ei[E + e];   // col (neighbor)
            unsigned int bit = 1u << (c & 31);
            unsigned int old = atomicOr(&bits[r * WORDS_PER_ROW + (c >> 5)], bit);
            if (!(old & bit)) {                    // first sighting of (r,c)
                int pos = atomicAdd(&cnt[r], 1);
                if (pos < MAXD) adj[r * MAXD + pos] = c;
            }
        }
        return;
    }

    // ---- Wh branch ----
    int node_base = (blockIdx.x - SCATTER_BLOCKS) * WH_NPB;
    for (int idx = tid; idx < H_HEADS * IN_FEAT * OUT_FEAT; idx += 256) {
        int hh = idx >> 10, f = (idx >> 4) & 63, o = idx & 15;
        Wt[hh][o][f] = W[idx];           // transpose: coalesced global read
    }
    for (int idx = tid; idx < WH_NPB * IN_FEAT; idx += 256)
        hs[idx >> 6][idx & 63] = hfeat[node_base * IN_FEAT + idx];
    __syncthreads();

    int ng = tid >> 7;             // 0/1: which half of the nodes
    int hh = (tid >> 4) & 7;
    int o  = tid & 15;
    float a1v = a[hh * 2 * OUT_FEAT + o];
    float a2v = a[hh * 2 * OUT_FEAT + OUT_FEAT + o];

    float4 w[16];
#pragma unroll
    for (int q = 0; q < 16; ++q)
        w[q] = *(const float4*)&Wt[hh][o][4 * q];

    for (int n = ng; n < WH_NPB; n += 2) {
        float acc = 0.f;
#pragma unroll
        for (int q = 0; q < 16; ++q) {
            float4 hv = *(const float4*)&hs[n][4 * q];
            acc = fmaf(hv.x, w[q].x, acc);
            acc = fmaf(hv.y, w[q].y, acc);
            acc = fmaf(hv.z, w[q].z, acc);
            acc = fmaf(hv.w, w[q].w, acc);
        }
        int node = node_base + n;
        Wh[(hh * N_NODES + node) * OUT_FEAT + o] = acc;
        float p1 = acc * a1v, p2 = acc * a2v;
#pragma unroll
        for (int m = 1; m < 16; m <<= 1) {
            p1 += __shfl_xor(p1, m, 64);
            p2 += __shfl_xor(p2, m, 64);
        }
        if (o == 0) {
            e1t[node * H_HEADS + hh] = p1;   // head-minor
            e2t[node * H_HEADS + hh] = p2;
        }
    }
}

// ---------------------------------------------------------------------------
// One row per 256-thread block. Critical path: cnt -> adj -> {S, e2t} gathers
// -> one barrier -> half-wave-per-head softmax (p = exp(v) directly; |v|<~55
// so fp32 exp is safe) -> aggregation. Head-major LDS rows: stride-1 lanes.
// ---------------------------------------------------------------------------
__launch_bounds__(256)
__global__ void gat_main_kernel(const int* __restrict__ cnts,
                                const int* __restrict__ adj,
                                const float* __restrict__ S,
                                const float* __restrict__ Wh,
                                const float* __restrict__ e1t,
                                const float* __restrict__ e2t,
                                const float* __restrict__ raw_gamma,
                                float* __restrict__ out) {
    __shared__ int lds_j[MAXD];
    __shared__ float lds_s[MAXD];
    __shared__ float lds_e2h[H_HEADS][MAXD];
    __shared__ float lds_p[H_HEADS][MAXD];
    __shared__ int fb_j;
    int i = blockIdx.x;
    int tid = threadIdx.x;
    int wave = tid >> 6, lane = tid & 63;

    int cnt = cnts[i];
    if (cnt > MAXD) cnt = MAXD;

    // ---- Phase A: parallel list load + gathers (first cnt threads) ----
    if (tid < cnt) {
        int j = adj[i * MAXD + tid];
        lds_j[tid] = j;
        lds_s[tid] = S[i * N_NODES + j];
        const float4* ep = (const float4*)&e2t[j * H_HEADS];
        float4 ea = ep[0], eb = ep[1];
        lds_e2h[0][tid] = ea.x; lds_e2h[1][tid] = ea.y;
        lds_e2h[2][tid] = ea.z; lds_e2h[3][tid] = ea.w;
        lds_e2h[4][tid] = eb.x; lds_e2h[5][tid] = eb.y;
        lds_e2h[6][tid] = eb.z; lds_e2h[7][tid] = eb.w;
    }
    __syncthreads();

    // ---- Degenerate row: softmax of all-masked row is one-hot at argmin S ----
    if (cnt == 0) {                      // block-uniform branch
        if (wave == 0) {
            float bm = 3.4e38f; int bj = 0;
            for (int j = lane; j < N_NODES; j += 64) {
                float sv = S[i * N_NODES + j];
                if (sv < bm) { bm = sv; bj = j; }
            }
            for (int m = 1; m < 64; m <<= 1) {
                float bm2 = __shfl_xor(bm, m, 64);
                int bj2 = __shfl_xor(bj, m, 64);
                if (bm2 < bm || (bm2 == bm && bj2 < bj)) { bm = bm2; bj = bj2; }
            }
            if (lane == 0) fb_j = bj;
        }
        __syncthreads();
        int jj = fb_j;
        if (tid < H_HEADS * OUT_FEAT) {
            int h2 = tid >> 4, o2 = tid & 15;
            float x = Wh[(h2 * N_NODES + jj) * OUT_FEAT + o2];
            out[i * (H_HEADS * OUT_FEAT) + h2 * OUT_FEAT + o2] =
                x > 0.f ? x : __expf(x) - 1.f;
        }
        return;
    }

    // ---- Phase B: half-wave per head ----
    int half = lane >> 5;
    int hl = lane & 31;
    int hh = wave * 2 + half;
    float g = log1pf(__expf(raw_gamma[hh]));       // softplus
    float e1v = e1t[i * H_HEADS + hh];
    float l = 0.f;
    for (int k = hl; k < cnt; k += 32) {
        float x = e1v + lds_e2h[hh][k];
        x = x > 0.f ? x : 0.2f * x;                // leaky_relu(., 0.2)
        float p = __expf(x * (1.f + g * lds_s[k]));
        lds_p[hh][k] = p;
        l += p;
    }
#pragma unroll
    for (int m = 1; m < 32; m <<= 1)               // stays within half-wave
        l += __shfl_xor(l, m, 64);

    // ---- aggregation: half-wave = 2 kgrps x 16 features ----
    int kgrp = hl >> 4, o = hl & 15;
    float acc = 0.f;
    for (int kk = kgrp; kk < cnt; kk += 2)
        acc = fmaf(lds_p[hh][kk], Wh[(hh * N_NODES + lds_j[kk]) * OUT_FEAT + o], acc);
    acc += __shfl_xor(acc, 16, 64);
    if (kgrp == 0) {
        float x = acc / l;
        out[i * (H_HEADS * OUT_FEAT) + hh * OUT_FEAT + o] =
            x > 0.f ? x : __expf(x) - 1.f;         // elu
    }
}

extern "C" void kernel_launch(void* const* d_in, const int* in_sizes, int n_in,
                              void* d_out, int out_size, void* d_ws, size_t ws_size,
                              hipStream_t stream) {
    const float* hfeat = (const float*)d_in[0];
    const int* ei      = (const int*)d_in[1];
    const float* S     = (const float*)d_in[2];
    const float* W     = (const float*)d_in[3];
    const float* a     = (const float*)d_in[4];
    const float* rg    = (const float*)d_in[5];
    float* out = (float*)d_out;

    char* ws = (char*)d_ws;
    // ws layout: cnt 12,288 | bits 1,179,648 | adj 1,179,648 | Wh 1,572,864 | e1t 98,304 | e2t 98,304
    int* cnt = (int*)ws;
    unsigned int* bits = (unsigned int*)(ws + 12288);
    int* adj = (int*)(ws + 12288 + 1179648);
    float* Wh = (float*)(ws + 12288 + 2 * 1179648);
    float* e1t = (float*)(ws + 12288 + 2 * 1179648 + 1572864);
    float* e2t = e1t + N_NODES * H_HEADS;

    // one memset covers cnt + bits (contiguous)
    hipMemsetAsync(ws, 0, 12288 + 1179648, stream);

    int E = in_sizes[1] / 2;
    scatter_and_wh_kernel<<<SCATTER_BLOCKS + WH_BLOCKS, 256, 0, stream>>>(
        ei, E, cnt, bits, adj, hfeat, W, a, Wh, e1t, e2t);

    gat_main_kernel<<<N_NODES, 256, 0, stream>>>(cnt, adj, S, Wh, e1t, e2t, rg, out);
}

// Round 7
// 112.298 us; speedup vs baseline: 1.0724x; 1.0724x over previous
//
#include <hip/hip_runtime.h>
#include <math.h>

#define N_NODES 3072
#define H_HEADS 8
#define IN_FEAT 64
#define OUT_FEAT 16
#define WORDS_PER_ROW 96               // 3072/32
#define MAXD 96                        // list cap; distinct-degree ~32, P(>96) ~ 1e-19
#define SCATTER_BLOCKS 384             // 384*256 = 98304 = E
#define WH_NPB 16                      // nodes per block in the Wh branch
#define WH_BLOCKS (N_NODES / WH_NPB)   // 192

// ---------------------------------------------------------------------------
// Fused: blocks [0, SCATTER_BLOCKS) scatter edges into the adjacency bitmask
// (single atomicOr per edge — bitmask dedups duplicates for free);
// blocks [SCATTER_BLOCKS, ...) compute Wh (head-major, for aggregation reads)
// and e1t/e2t (head-minor, so main gathers all 8 heads in one 32B read).
// ---------------------------------------------------------------------------
__launch_bounds__(256)
__global__ void scatter_and_wh_kernel(const int* __restrict__ ei, int E,
                                      unsigned int* __restrict__ bits,
                                      const float* __restrict__ hfeat,
                                      const float* __restrict__ W,
                                      const float* __restrict__ a,
                                      float* __restrict__ Wh,
                                      float* __restrict__ e1t,
                                      float* __restrict__ e2t) {
    __shared__ __align__(16) float Wt[H_HEADS][OUT_FEAT][68];  // pad 64->68: no 2^k stride
    __shared__ __align__(16) float hs[WH_NPB][IN_FEAT];

    int tid = threadIdx.x;
    if (blockIdx.x < SCATTER_BLOCKS) {
        int e = blockIdx.x * 256 + tid;
        if (e < E) {
            int r = ei[e];       // row (softmax source)
            int c = ei[E + e];   // col (neighbor)
            atomicOr(&bits[r * WORDS_PER_ROW + (c >> 5)], 1u << (c & 31));
        }
        return;
    }

    // ---- Wh branch ----
    int node_base = (blockIdx.x - SCATTER_BLOCKS) * WH_NPB;
    for (int idx = tid; idx < H_HEADS * IN_FEAT * OUT_FEAT; idx += 256) {
        int hh = idx >> 10, f = (idx >> 4) & 63, o = idx & 15;
        Wt[hh][o][f] = W[idx];           // transpose: coalesced global read
    }
    for (int idx = tid; idx < WH_NPB * IN_FEAT; idx += 256)
        hs[idx >> 6][idx & 63] = hfeat[node_base * IN_FEAT + idx];
    __syncthreads();

    int ng = tid >> 7;             // 0/1: which half of the nodes
    int hh = (tid >> 4) & 7;
    int o  = tid & 15;
    float a1v = a[hh * 2 * OUT_FEAT + o];
    float a2v = a[hh * 2 * OUT_FEAT + OUT_FEAT + o];

    float4 w[16];
#pragma unroll
    for (int q = 0; q < 16; ++q)
        w[q] = *(const float4*)&Wt[hh][o][4 * q];

    for (int n = ng; n < WH_NPB; n += 2) {
        float acc = 0.f;
#pragma unroll
        for (int q = 0; q < 16; ++q) {
            float4 hv = *(const float4*)&hs[n][4 * q];
            acc = fmaf(hv.x, w[q].x, acc);
            acc = fmaf(hv.y, w[q].y, acc);
            acc = fmaf(hv.z, w[q].z, acc);
            acc = fmaf(hv.w, w[q].w, acc);
        }
        int node = node_base + n;
        Wh[(hh * N_NODES + node) * OUT_FEAT + o] = acc;
        float p1 = acc * a1v, p2 = acc * a2v;
#pragma unroll
        for (int m = 1; m < 16; m <<= 1) {
            p1 += __shfl_xor(p1, m, 64);
            p2 += __shfl_xor(p2, m, 64);
        }
        if (o == 0) {
            e1t[node * H_HEADS + hh] = p1;   // head-minor
            e2t[node * H_HEADS + hh] = p2;
        }
    }
}

// ---------------------------------------------------------------------------
// One row per 256-thread block. Wave 0 decodes the bitmask row (popc +
// 6-step shuffle prefix scan) into lds_j; then all threads gather S and the
// 8-head e2t vector per neighbor in parallel; then half-wave-per-head
// softmax (p = exp(v) directly; |v| <~ 55 so fp32 exp is safe) + aggregation.
// ---------------------------------------------------------------------------
__launch_bounds__(256)
__global__ void gat_main_kernel(const unsigned int* __restrict__ bits,
                                const float* __restrict__ S,
                                const float* __restrict__ Wh,
                                const float* __restrict__ e1t,
                                const float* __restrict__ e2t,
                                const float* __restrict__ raw_gamma,
                                float* __restrict__ out) {
    __shared__ int lds_j[MAXD];
    __shared__ float lds_s[MAXD];
    __shared__ float lds_e2h[H_HEADS][MAXD];
    __shared__ float lds_p[H_HEADS][MAXD];
    __shared__ int lds_cnt;
    __shared__ int fb_j;
    int i = blockIdx.x;
    int tid = threadIdx.x;
    int wave = tid >> 6, lane = tid & 63;

    // ---- Phase A1: wave 0 decodes the bitmask row into lds_j ----
    if (wave == 0) {
        unsigned int w0 = bits[i * WORDS_PER_ROW + lane];
        unsigned int w1 = (lane < WORDS_PER_ROW - 64)
                              ? bits[i * WORDS_PER_ROW + 64 + lane] : 0u;
        int c = __popc(w0) + __popc(w1);
        int s = c;
#pragma unroll
        for (int d = 1; d < 64; d <<= 1) {
            int v = __shfl_up(s, d, 64);
            if (lane >= d) s += v;
        }
        int off = s - c;                     // exclusive prefix
        if (lane == 63) lds_cnt = s;         // total
        unsigned int b = w0;
        int base = lane << 5;
        while (b) {
            int bit = __ffs(b) - 1; b &= b - 1;
            if (off < MAXD) lds_j[off] = base + bit;
            ++off;
        }
        b = w1; base = (64 + lane) << 5;
        while (b) {
            int bit = __ffs(b) - 1; b &= b - 1;
            if (off < MAXD) lds_j[off] = base + bit;
            ++off;
        }
    }
    __syncthreads();
    int cnt = lds_cnt;
    if (cnt > MAXD) cnt = MAXD;

    // ---- Phase A2: parallel gathers (S + all-heads e2t per neighbor) ----
    if (tid < cnt) {
        int j = lds_j[tid];
        lds_s[tid] = S[i * N_NODES + j];
        const float4* ep = (const float4*)&e2t[j * H_HEADS];
        float4 ea = ep[0], eb = ep[1];
        lds_e2h[0][tid] = ea.x; lds_e2h[1][tid] = ea.y;
        lds_e2h[2][tid] = ea.z; lds_e2h[3][tid] = ea.w;
        lds_e2h[4][tid] = eb.x; lds_e2h[5][tid] = eb.y;
        lds_e2h[6][tid] = eb.z; lds_e2h[7][tid] = eb.w;
    }
    __syncthreads();

    // ---- Degenerate row: softmax of all-masked row is one-hot at argmin S ----
    if (cnt == 0) {                      // block-uniform branch
        if (wave == 0) {
            float bm = 3.4e38f; int bj = 0;
            for (int j = lane; j < N_NODES; j += 64) {
                float sv = S[i * N_NODES + j];
                if (sv < bm) { bm = sv; bj = j; }
            }
            for (int m = 1; m < 64; m <<= 1) {
                float bm2 = __shfl_xor(bm, m, 64);
                int bj2 = __shfl_xor(bj, m, 64);
                if (bm2 < bm || (bm2 == bm && bj2 < bj)) { bm = bm2; bj = bj2; }
            }
            if (lane == 0) fb_j = bj;
        }
        __syncthreads();
        int jj = fb_j;
        if (tid < H_HEADS * OUT_FEAT) {
            int h2 = tid >> 4, o2 = tid & 15;
            float x = Wh[(h2 * N_NODES + jj) * OUT_FEAT + o2];
            out[i * (H_HEADS * OUT_FEAT) + h2 * OUT_FEAT + o2] =
                x > 0.f ? x : __expf(x) - 1.f;
        }
        return;
    }

    // ---- Phase B: half-wave per head ----
    int half = lane >> 5;
    int hl = lane & 31;
    int hh = wave * 2 + half;
    float g = log1pf(__expf(raw_gamma[hh]));       // softplus
    float e1v = e1t[i * H_HEADS + hh];
    float l = 0.f;
    for (int k = hl; k < cnt; k += 32) {
        float x = e1v + lds_e2h[hh][k];
        x = x > 0.f ? x : 0.2f * x;                // leaky_relu(., 0.2)
        float p = __expf(x * (1.f + g * lds_s[k]));
        lds_p[hh][k] = p;
        l += p;
    }
#pragma unroll
    for (int m = 1; m < 32; m <<= 1)               // stays within half-wave
        l += __shfl_xor(l, m, 64);

    // ---- aggregation: half-wave = 2 kgrps x 16 features ----
    int kgrp = hl >> 4, o = hl & 15;
    float acc = 0.f;
    for (int kk = kgrp; kk < cnt; kk += 2)
        acc = fmaf(lds_p[hh][kk], Wh[(hh * N_NODES + lds_j[kk]) * OUT_FEAT + o], acc);
    acc += __shfl_xor(acc, 16, 64);
    if (kgrp == 0) {
        float x = acc / l;
        out[i * (H_HEADS * OUT_FEAT) + hh * OUT_FEAT + o] =
            x > 0.f ? x : __expf(x) - 1.f;         // elu
    }
}

extern "C" void kernel_launch(void* const* d_in, const int* in_sizes, int n_in,
                              void* d_out, int out_size, void* d_ws, size_t ws_size,
                              hipStream_t stream) {
    const float* hfeat = (const float*)d_in[0];
    const int* ei      = (const int*)d_in[1];
    const float* S     = (const float*)d_in[2];
    const float* W     = (const float*)d_in[3];
    const float* a     = (const float*)d_in[4];
    const float* rg    = (const float*)d_in[5];
    float* out = (float*)d_out;

    char* ws = (char*)d_ws;
    // ws layout: bits 1,179,648 | Wh 1,572,864 | e1t 98,304 | e2t 98,304
    unsigned int* bits = (unsigned int*)ws;
    float* Wh = (float*)(ws + 1179648);
    float* e1t = (float*)(ws + 1179648 + 1572864);
    float* e2t = e1t + N_NODES * H_HEADS;

    hipMemsetAsync(bits, 0, (size_t)N_NODES * WORDS_PER_ROW * 4, stream);

    int E = in_sizes[1] / 2;
    scatter_and_wh_kernel<<<SCATTER_BLOCKS + WH_BLOCKS, 256, 0, stream>>>(
        ei, E, bits, hfeat, W, a, Wh, e1t, e2t);

    gat_main_kernel<<<N_NODES, 256, 0, stream>>>(bits, S, Wh, e1t, e2t, rg, out);
}